// Round 21
// baseline (75.436 us; speedup 1.0000x reference)
//
#include <hip/hip_runtime.h>

#define HW 16384        // 128*128
#define PADPIX 16900    // 130*130 padded pixel count

typedef __attribute__((ext_vector_type(8))) short short8v;
typedef __attribute__((ext_vector_type(4))) float f32x4;

__device__ inline short bf16rne(float x) {
    unsigned u = __float_as_uint(x);
    unsigned r = (u + 0x7fffu + ((u >> 16) & 1u)) >> 16;
    return (short)r;
}
__device__ inline float bf16tof(short s) {
    return __uint_as_float(((unsigned)(unsigned short)s) << 16);
}

// padded-pixel index for border element j (j in 0..515)
__device__ inline int border_pp(int j) {
    if (j < 130) return j;                          // row 0
    if (j < 260) return 129 * 130 + (j - 130);      // row 129
    if (j < 388) return (j - 259) * 130;            // col 0, rows 1..128
    return (j - 387) * 130 + 129;                   // col 129, rows 1..128
}

// ===== K1: weight prep (0..467) + borders (468..564) =========================
__global__ __launch_bounds__(256) void k1_kernel(
    const float* __restrict__ W1, const float* __restrict__ W2,
    const float* __restrict__ Wk,
    short* __restrict__ Wb1, short* __restrict__ Wb2, short* __restrict__ Wbk,
    short* __restrict__ hcatN, short* __restrict__ h1N)
{
    int bid = blockIdx.x;
    const int t = threadIdx.x;
    if (bid < 468) {
        const float* W; short* Wb; int CIN, COUT, idx;
        if (bid < 288)      { W = W1; Wb = Wb1; CIN = 128; COUT = 64; idx = bid * 256 + t; }
        else if (bid < 432) { W = W2; Wb = Wb2; CIN = 64;  COUT = 64; idx = (bid - 288) * 256 + t; }
        else                { W = Wk; Wb = Wbk; CIN = 64;  COUT = 16; idx = (bid - 432) * 256 + t; }
        int NOCT = COUT >> 4, NCH = CIN >> 5;
        int total = 9 * NCH * NOCT * 512;
        if (idx >= total) return;
        int j = idx & 7, l = (idx >> 3) & 63;
        int rest = idx >> 9;
        int oct = rest % NOCT; rest /= NOCT;
        int ch = rest % NCH;
        int tap = rest / NCH;
        int o = oct * 16 + (l & 15);
        int c = ch * 32 + (l >> 4) * 8 + j;
        Wb[idx] = bf16rne(W[((size_t)o * CIN + c) * 9 + tap]);
        return;
    }
    // ---- zero borders of hcatN (16512 int4) and h1N (8256 int4) ----
    int t2 = (bid - 468) * 256 + t;
    const int4 z = make_int4(0, 0, 0, 0);
    if (t2 < 16512) {
        int px = t2 >> 4, q = t2 & 15;
        int b = px >= 516; int j = px - b * 516;
        int pp = border_pp(j);
        ((int4*)hcatN)[((size_t)b * PADPIX + pp) * 16 + q] = z;
    } else if (t2 < 24768) {
        int idx = t2 - 16512;
        int px = idx >> 3, q = idx & 7;
        int b = px >= 516; int j = px - b * 516;
        int pp = border_pp(j);
        ((int4*)h1N)[((size_t)b * PADPIX + pp) * 8 + q] = z;
    }
}

// ===== front: upsample -> (Kf MFMA || qconv) -> gate -> hcatN, all in LDS ====
#define UPSTR 72                 // ch-stride of upB in shorts (16B-aligned)
#define UPROW (34 * UPSTR)       // shorts per upB row (34 lpx)
__global__ __launch_bounds__(256) void front_kernel(
    const float* __restrict__ x1, const short* __restrict__ Wbk,
    const float* __restrict__ bk, const float* __restrict__ Wq,
    const float* __restrict__ bq, const float* __restrict__ x2,
    const float* __restrict__ Wv, const float* __restrict__ bv,
    short* __restrict__ hcatN)
{
    __shared__ __align__(16) short upB[3 * UPROW];   // [r][lpx 0..33][ch 0..63]
    __shared__ float kfs[16 * 33];                   // [k][px 0..31], stride 33
    __shared__ float qbuf[32 * 65];                  // [px][ch], stride 65
    __shared__ int tr[32 * 33];                      // [chpair][px], stride 33
    int bid = blockIdx.x;
    const int xq = bid & 3;
    const int y = (bid >> 2) & 127;
    const int b = bid >> 9;
    const int t = threadIdx.x;
    const int X0 = xq * 32;

    // ---- phase 1: upsample rows y-1..y+1 (bf16) into upB, zeros outside ----
    {
        const int px1 = t & 31, cg1 = t >> 5;        // 32 px x 8 ch-groups
        const int gx = X0 + px1;
        float fx = (float)(gx * 63) / 127.f;
        int x0 = (int)fx; float wx = fx - (float)x0; int x1i = min(x0 + 1, 63);
        #pragma unroll
        for (int r = 0; r < 3; r++) {
            int ry = y + r - 1;
            bool rv = ((unsigned)ry < 128u);
            int ryc = rv ? ry : 0;
            float fy = (float)(ryc * 63) / 127.f;
            int y0 = (int)fy; float wy = fy - (float)y0; int y1 = min(y0 + 1, 63);
            int pk[4];
            #pragma unroll
            for (int jj = 0; jj < 4; jj++) {
                unsigned lohi[2];
                #pragma unroll
                for (int h = 0; h < 2; h++) {
                    int ch = cg1 * 8 + jj * 2 + h;
                    float v = 0.f;
                    if (rv) {
                        const float* sp = x1 + ((size_t)(b * 64 + ch) << 12);
                        float v00 = sp[(y0 << 6) + x0], v01 = sp[(y0 << 6) + x1i];
                        float v10 = sp[(y1 << 6) + x0], v11 = sp[(y1 << 6) + x1i];
                        float top = v00 * (1.f - wx) + v01 * wx;
                        float bot = v10 * (1.f - wx) + v11 * wx;
                        v = top * (1.f - wy) + bot * wy;
                    }
                    lohi[h] = (unsigned)(unsigned short)bf16rne(v);
                }
                pk[jj] = (int)(lohi[0] | (lohi[1] << 16));
            }
            *(int4*)(upB + r * UPROW + (px1 + 1) * UPSTR + cg1 * 8) =
                make_int4(pk[0], pk[1], pk[2], pk[3]);
        }
        if (t < 48) {                                // halo: r x side x cg
            int r = t >> 4, side = (t >> 3) & 1, cg = t & 7;
            int gxh = X0 + (side ? 32 : -1);
            int lpx = side ? 33 : 0;
            int ry = y + r - 1;
            bool v_ok = ((unsigned)ry < 128u) && ((unsigned)gxh < 128u);
            int ryc = ((unsigned)ry < 128u) ? ry : 0;
            float fy = (float)(ryc * 63) / 127.f;
            int y0 = (int)fy; float wy = fy - (float)y0; int y1 = min(y0 + 1, 63);
            int gxc = min(max(gxh, 0), 127);
            float fxh = (float)(gxc * 63) / 127.f;
            int hx0 = (int)fxh; float hwx = fxh - (float)hx0; int hx1 = min(hx0 + 1, 63);
            int pk[4];
            #pragma unroll
            for (int jj = 0; jj < 4; jj++) {
                unsigned lohi[2];
                #pragma unroll
                for (int h = 0; h < 2; h++) {
                    int ch = cg * 8 + jj * 2 + h;
                    float v = 0.f;
                    if (v_ok) {
                        const float* sp = x1 + ((size_t)(b * 64 + ch) << 12);
                        float v00 = sp[(y0 << 6) + hx0], v01 = sp[(y0 << 6) + hx1];
                        float v10 = sp[(y1 << 6) + hx0], v11 = sp[(y1 << 6) + hx1];
                        float top = v00 * (1.f - hwx) + v01 * hwx;
                        float bot = v10 * (1.f - hwx) + v11 * hwx;
                        v = top * (1.f - wy) + bot * wy;
                    }
                    lohi[h] = (unsigned)(unsigned short)bf16rne(v);
                }
                pk[jj] = (int)(lohi[0] | (lohi[1] << 16));
            }
            *(int4*)(upB + r * UPROW + lpx * UPSTR + cg * 8) =
                make_int4(pk[0], pk[1], pk[2], pk[3]);
        }
    }
    __syncthreads();

    // ---- phase 2: waves 0-1: Kf MFMA (16 px each); waves 2-3: qconv --------
    {
        const int w = t >> 6, l = t & 63;
        if (w < 2) {
            const int lx = l & 15, kg = l >> 4;
            const short* wbase = Wbk + (size_t)l * 8;
            f32x4 acc = (f32x4)(0.f);
            #pragma unroll
            for (int ty = 0; ty < 3; ty++) {
                #pragma unroll
                for (int tx = 0; tx < 3; tx++) {
                    const short* ab = upB + ty * UPROW + (size_t)(w * 16 + lx + tx) * UPSTR;
                    #pragma unroll
                    for (int ch = 0; ch < 2; ch++) {
                        short8v a = *(const short8v*)(ab + kg * 8 + ch * 32);
                        short8v bf = *(const short8v*)(wbase +
                            (size_t)((ty * 3 + tx) * 2 + ch) * 512);
                        acc = __builtin_amdgcn_mfma_f32_16x16x32_bf16(a, bf, acc, 0, 0, 0);
                    }
                }
            }
            float bb = bk[lx];
            #pragma unroll
            for (int r = 0; r < 4; r++)
                kfs[lx * 33 + (w * 16 + kg * 4 + r)] = fmaxf(acc[r] + bb, 0.f);
        } else {
            // depthwise qconv, ch-major sliding window (conflict-free LDS reads)
            const int ch = l;
            const int px0 = (w - 2) * 16;
            const float* wqp = Wq + ch * 9;
            float wq[9];
            #pragma unroll
            for (int i = 0; i < 9; i++) wq[i] = wqp[i];
            float bqc = bq[ch];
            float a0[3], a1[3];
            #pragma unroll
            for (int r = 0; r < 3; r++) {
                a0[r] = bf16tof(upB[r * UPROW + px0 * UPSTR + ch]);
                a1[r] = bf16tof(upB[r * UPROW + (px0 + 1) * UPSTR + ch]);
            }
            for (int p = 0; p < 16; p++) {
                float a2[3];
                #pragma unroll
                for (int r = 0; r < 3; r++)
                    a2[r] = bf16tof(upB[r * UPROW + (px0 + p + 2) * UPSTR + ch]);
                float q = bqc;
                #pragma unroll
                for (int r = 0; r < 3; r++)
                    q = fmaf(a0[r], wq[r * 3 + 0],
                        fmaf(a1[r], wq[r * 3 + 1], fmaf(a2[r], wq[r * 3 + 2], q)));
                qbuf[(px0 + p) * 65 + ch] = fmaxf(q, 0.f);
                #pragma unroll
                for (int r = 0; r < 3; r++) { a0[r] = a1[r]; a1[r] = a2[r]; }
            }
        }
    }
    __syncthreads();

    // ---- phase 3: softmax gate, 32 px x 64 ch -------------------------------
    {
        const int px = t & 31, cg = t >> 5;
        const int x = X0 + px;
        float kv[16];
        #pragma unroll
        for (int k = 0; k < 16; k++) kv[k] = kfs[k * 33 + px];
        float kvmax = kv[0];
        #pragma unroll
        for (int k = 1; k < 16; k++) kvmax = fmaxf(kvmax, kv[k]);
        float wvv[16], bvv[16];
        #pragma unroll
        for (int k = 0; k < 16; k++) { wvv[k] = Wv[k]; bvv[k] = bv[k]; }
        float xvv[8], qv[8];
        #pragma unroll
        for (int j = 0; j < 8; j++) {
            xvv[j] = x2[((size_t)(b * 64 + cg * 8 + j) << 14) + (y << 7) + x];
            qv[j] = qbuf[px * 65 + cg * 8 + j];
        }
        #pragma unroll
        for (int jj = 0; jj < 4; jj++) {
            int gpk = 0;
            #pragma unroll
            for (int h = 0; h < 2; h++) {
                const int j = jj * 2 + h;
                float q = qv[j];
                float mx = q * kvmax;                // q,kv >= 0 => exact max
                float den = 0.f, num = 0.f;
                #pragma unroll
                for (int k = 0; k < 16; k++) {
                    float e = __expf(fmaf(q, kv[k], -mx));
                    den += e;
                    float V = fmaxf(fmaf(xvv[j], wvv[k], bvv[k]), 0.f);
                    num = fmaf(e, V, num);
                }
                unsigned u = (unsigned)(unsigned short)bf16rne(num / den);
                gpk |= (int)(u << (h * 16));
            }
            tr[(cg * 4 + jj) * 33 + px] = gpk;
        }
    }
    __syncthreads();

    // ---- phase 4: coalesced writes: gate -> ch 0..63, upB row1 -> ch 64..127
    {
        const int px4 = t >> 3, cq = t & 7;
        int pp = (y + 1) * 130 + X0 + px4 + 1;
        int wd[4];
        #pragma unroll
        for (int i = 0; i < 4; i++) wd[i] = tr[(cq * 4 + i) * 33 + px4];
        int* dpL = (int*)hcatN + ((size_t)b * PADPIX + pp) * 64 + cq * 4;
        *(int4*)dpL = make_int4(wd[0], wd[1], wd[2], wd[3]);
        const short* us = upB + UPROW + (size_t)(px4 + 1) * UPSTR + cq * 8;
        int4 u = *(const int4*)us;
        int* dpU = (int*)hcatN + ((size_t)b * PADPIX + pp) * 64 + 32 + cq * 4;
        *(int4*)dpU = u;
    }
}

// ===== MFMA implicit-GEMM 3x3 conv, LDS-staged A-slab, 2 rows/block ==========
// Stages 4 padded rows; each B-fragment feeds 2 MFMAs (rows y, y+1) -> half
// the B L2 traffic. PADOUT: padded NHWC out (borders stay 0); else flat NHWC.
// INBN: BN(scale,shift)+relu applied inline while staging (borders -> 0).
template<int PSTR, int LDSTR, int CIN, int COUT, int NWN, int OPW,
         bool PADOUT, bool INBN>
__global__ __launch_bounds__(256) void convmfma_kernel(
    const short* __restrict__ actN, const short* __restrict__ Wb,
    short* __restrict__ dstB,
    const float* __restrict__ statsAcc,
    const float* __restrict__ g, const float* __restrict__ beta,
    float* __restrict__ partials)
{
    constexpr int NCH = CIN / 32, NOCT = COUT / 16, NWM = 4 / NWN;
    constexpr int EXT = NWM * 16;
    constexpr int SEG = 128 / EXT;
    __shared__ __align__(16) short slab[4 * 34 * LDSTR];
    __shared__ float scsh[INBN ? 128 : 2];
    const int t = threadIdx.x;
    const int w = t >> 6, l = t & 63;
    const int wn = w % NWN, wm = w / NWN;
    int bid = blockIdx.x;
    const int xseg = bid % SEG; bid /= SEG;
    const int y = (bid & 63) * 2;                    // row pair y, y+1
    const int b = bid >> 6;
    const int lx = l & 15, kg = l >> 4;
    const int X0 = xseg * EXT;

    if (INBN) {
        if (t < 64) {
            float mean = statsAcc[t * 2] * (1.f / 32768.f);
            float var  = statsAcc[t * 2 + 1] * (1.f / 32768.f) - mean * mean;
            float sc = g[t] * rsqrtf(var + 1e-5f);
            scsh[t] = sc;
            scsh[64 + t] = beta[t] - mean * sc;
        }
        __syncthreads();
    }

    // ---- stage 4 rows x 34 px x CIN into LDS (all in-bounds of padded buf) --
    constexpr int ROWI4 = 34 * PSTR / 8;             // int4 per slab row
    constexpr int PXI4 = PSTR / 8;                   // int4 per pixel (pow2)
    #pragma unroll
    for (int r = 0; r < 4; r++) {
        const int prow = y + r;                      // padded row 0..129
        const bool rowb = (prow == 0) || (prow == 129);
        const int4* src = (const int4*)(actN +
            ((size_t)b * PADPIX + (size_t)prow * 130 + X0) * PSTR);
        for (int i = t; i < ROWI4; i += 256) {
            int p = i / PXI4, cq = i % PXI4;
            int4 v = src[i];
            if (INBN) {
                int pcol = X0 + p;                   // padded col 0..129
                if (rowb || pcol == 0 || pcol == 129) {
                    v = make_int4(0, 0, 0, 0);
                } else {
                    int ch0 = cq * 8;
                    int* vw = (int*)&v;
                    #pragma unroll
                    for (int wd = 0; wd < 4; wd++) {
                        int c0 = ch0 + wd * 2, c1 = c0 + 1;
                        float lo = bf16tof((short)(vw[wd] & 0xFFFF));
                        float hi = bf16tof((short)((unsigned)vw[wd] >> 16));
                        lo = fmaxf(fmaf(lo, scsh[c0], scsh[64 + c0]), 0.f);
                        hi = fmaxf(fmaf(hi, scsh[c1], scsh[64 + c1]), 0.f);
                        unsigned ulo = (unsigned)(unsigned short)bf16rne(lo);
                        unsigned uhi = (unsigned)(unsigned short)bf16rne(hi);
                        vw[wd] = (int)(ulo | (uhi << 16));
                    }
                }
            }
            *(int4*)(slab + (r * 34 + p) * LDSTR + cq * 8) = v;
        }
    }
    __syncthreads();

    const short* wbase = Wb + (size_t)(wn * OPW) * 512 + (size_t)l * 8;

    f32x4 acc[2][OPW];
    #pragma unroll
    for (int m = 0; m < 2; m++)
        #pragma unroll
        for (int p = 0; p < OPW; p++) acc[m][p] = (f32x4)(0.f);

    #pragma unroll
    for (int ty = 0; ty < 3; ty++) {
        #pragma unroll
        for (int tx = 0; tx < 3; tx++) {
            const int tap = ty * 3 + tx;
            const short* ab0 = slab + ((ty    ) * 34 + wm * 16 + lx + tx) * LDSTR + kg * 8;
            const short* ab1 = slab + ((ty + 1) * 34 + wm * 16 + lx + tx) * LDSTR + kg * 8;
            #pragma unroll
            for (int ch = 0; ch < NCH; ch++) {
                short8v a0 = *(const short8v*)(ab0 + ch * 32);
                short8v a1 = *(const short8v*)(ab1 + ch * 32);
                #pragma unroll
                for (int p = 0; p < OPW; p++) {
                    short8v bf = *(const short8v*)(wbase +
                        (size_t)((tap * NCH + ch) * NOCT + p) * 512);
                    acc[0][p] = __builtin_amdgcn_mfma_f32_16x16x32_bf16(a0, bf, acc[0][p], 0, 0, 0);
                    acc[1][p] = __builtin_amdgcn_mfma_f32_16x16x32_bf16(a1, bf, acc[1][p], 0, 0, 0);
                }
            }
        }
    }

    // raw bf16 epilogue (unnormalized); PADOUT keeps zero borders intact
    #pragma unroll
    for (int m = 0; m < 2; m++) {
        #pragma unroll
        for (int p = 0; p < OPW; p++) {
            const int oc = (wn * OPW + p) * 16 + lx;
            #pragma unroll
            for (int r = 0; r < 4; r++) {
                const int px_x = X0 + wm * 16 + kg * 4 + r;
                size_t pix = PADOUT
                    ? ((size_t)b * PADPIX + (size_t)(y + m + 1) * 130 + px_x + 1)
                    : ((size_t)b * HW + (size_t)(y + m) * 128 + px_x);
                dstB[pix * COUT + oc] = bf16rne(acc[m][p][r]);
            }
        }
    }

    // per-wave BN partials (both rows summed; same oc), race-free plain stores
    #pragma unroll
    for (int p = 0; p < OPW; p++) {
        float s = 0.f, q2 = 0.f;
        #pragma unroll
        for (int m = 0; m < 2; m++) {
            f32x4 v = acc[m][p];
            #pragma unroll
            for (int r = 0; r < 4; r++) { s += v[r]; q2 = fmaf(v[r], v[r], q2); }
        }
        s += __shfl_xor(s, 16); q2 += __shfl_xor(q2, 16);
        s += __shfl_xor(s, 32); q2 += __shfl_xor(q2, 32);
        if (l < 16) {
            const int oc = (wn * OPW + p) * 16 + lx;
            float* dp = partials + (((size_t)blockIdx.x * NWM + wm) * 64 + oc) * 2;
            dp[0] = s;
            dp[1] = q2;
        }
    }
}

// ===== reduce NB partial pairs per channel -> raw sums (no atomics) ==========
__global__ void bnred_kernel(const float* __restrict__ partials, int nb,
                             float* __restrict__ statsAcc) {
    int ch = blockIdx.x;                                 // 64 blocks
    const int t = threadIdx.x;
    float s = 0.f, q = 0.f;
    for (int i = t; i < nb; i += 256) {
        const float* p = partials + ((size_t)i * 64 + ch) * 2;
        s += p[0];
        q += p[1];
    }
    __shared__ float sh[512];
    sh[t] = s;
    sh[256 + t] = q;
    __syncthreads();
    for (int off = 128; off > 0; off >>= 1) {
        if (t < off) {
            sh[t] += sh[t + off];
            sh[256 + t] += sh[256 + t + off];
        }
        __syncthreads();
    }
    if (t == 0) {
        statsAcc[ch * 2] = sh[0];
        statsAcc[ch * 2 + 1] = sh[256];
    }
}

// ===== BN2 finalize + relu on raw-bf16 NHWC, transpose, split -> d_out =======
__global__ __launch_bounds__(256) void norm2_kernel(
    const short* __restrict__ h2N, const float* __restrict__ statsAcc,
    const float* __restrict__ g, const float* __restrict__ beta,
    float* __restrict__ out)
{
    __shared__ float lds[64 * 33];
    __shared__ float scsh[128];
    int bid = blockIdx.x;
    const int chunk = bid & 511;                         // 512 chunks x 32 px
    const int b = bid >> 9;
    const int t = threadIdx.x;
    const int P0 = chunk * 32;
    if (t < 64) {
        float mean = statsAcc[t * 2] * (1.f / 32768.f);
        float var  = statsAcc[t * 2 + 1] * (1.f / 32768.f) - mean * mean;
        float sc = g[t] * rsqrtf(var + 1e-5f);
        scsh[t] = sc;
        scsh[64 + t] = beta[t] - mean * sc;
    }
    __syncthreads();
    {
        const int px = t >> 3, cq = t & 7;
        const short* sp = h2N + ((size_t)b * HW + P0 + px) * 64 + cq * 8;
        int4 v = *(const int4*)sp;
        const int* vw = (const int*)&v;
        #pragma unroll
        for (int wd = 0; wd < 4; wd++) {
            int c0 = cq * 8 + wd * 2, c1 = c0 + 1;
            float lo = bf16tof((short)(vw[wd] & 0xFFFF));
            float hi = bf16tof((short)((unsigned)vw[wd] >> 16));
            lds[c0 * 33 + px] = fmaxf(fmaf(lo, scsh[c0], scsh[64 + c0]), 0.f);
            lds[c1 * 33 + px] = fmaxf(fmaf(hi, scsh[c1], scsh[64 + c1]), 0.f);
        }
    }
    __syncthreads();
    {
        const int c = t >> 2, qx = t & 3;
        const float* r = lds + c * 33 + qx * 8;
        float4 o0, o1;
        o0.x = r[0]; o0.y = r[1]; o0.z = r[2]; o0.w = r[3];
        o1.x = r[4]; o1.y = r[5]; o1.z = r[6]; o1.w = r[7];
        int half = c >> 5, cc = c & 31;
        float* dp = out + (size_t)half * 1048576 + (((size_t)(b * 32 + cc)) << 14)
                  + P0 + qx * 8;
        *(float4*)dp = o0;
        *(float4*)(dp + 4) = o1;
    }
}

extern "C" void kernel_launch(void* const* d_in, const int* in_sizes, int n_in,
                              void* d_out, int out_size, void* d_ws, size_t ws_size,
                              hipStream_t stream) {
    const float* x1 = (const float*)d_in[0];
    // d_in[1] (x1_) is unused by the reference
    const float* x2 = (const float*)d_in[2];
    const float* Wq = (const float*)d_in[3];
    const float* bq = (const float*)d_in[4];
    const float* Wk = (const float*)d_in[5];
    const float* bk = (const float*)d_in[6];
    const float* Wv = (const float*)d_in[7];
    const float* bv = (const float*)d_in[8];
    const float* W1 = (const float*)d_in[9];
    const float* g1 = (const float*)d_in[10];
    const float* b1 = (const float*)d_in[11];
    const float* W2 = (const float*)d_in[12];
    const float* g2 = (const float*)d_in[13];
    const float* b2 = (const float*)d_in[14];
    float* out = (float*)d_out;
    float* ws = (float*)d_ws;

    // workspace layout (float offsets)
    float* stacc    = ws;                        // 256 raw sums (s1 @ +0, s2 @ +128)
    short* h2N      = (short*)(ws + 256);        // [2][HW][64] bf16  (1,048,576 f)
    short* hcatN    = (short*)(ws + 1048832);    // [2][PADPIX][128] bf16 (2,163,200 f)
    short* h1N      = (short*)(ws + 3212032);    // [2][PADPIX][64]  bf16 (1,081,600 f)
    short* Wb1      = (short*)(ws + 4293632);    // 73728 shorts = 36864 f
    short* Wb2      = (short*)(ws + 4330496);    // 36864 shorts = 18432 f
    short* Wbk      = (short*)(ws + 4348928);    // 9216 shorts  =  4608 f
    float* partials = ws + 4353536;              // 512*2*64*2 = 131,072 f used

    // K1: weight prep + border zeroing
    k1_kernel<<<565, 256, 0, stream>>>(W1, W2, Wk, Wb1, Wb2, Wbk, hcatN, h1N);

    // front: upsample + Kf conv + qconv + gate, fused -> hcatN (both halves)
    front_kernel<<<1024, 256, 0, stream>>>(x1, Wbk, bk, Wq, bq, x2, Wv, bv, hcatN);

    // conv1 128->64 (2 rows/block): raw bf16 -> padded NHWC h1N + partial stats
    convmfma_kernel<128, 136, 128, 64, 2, 2, true, false><<<512, 256, 0, stream>>>(
        hcatN, Wb1, h1N, nullptr, nullptr, nullptr, partials);
    bnred_kernel<<<64, 256, 0, stream>>>(partials, 1024, stacc);

    // conv2 64->64 (2 rows/block): BN1+relu inline staging; raw bf16 -> h2N
    convmfma_kernel<64, 72, 64, 64, 2, 2, false, true><<<512, 256, 0, stream>>>(
        h1N, Wb2, h2N, stacc, g1, b1, partials);
    bnred_kernel<<<64, 256, 0, stream>>>(partials, 1024, stacc + 128);

    // BN2 finalize + relu + transpose + split -> d_out
    norm2_kernel<<<1024, 256, 0, stream>>>(h2N, stacc + 128, g2, b2, out);
}

// Round 22
// 69.894 us; speedup vs baseline: 1.0793x; 1.0793x over previous
//
#include <hip/hip_runtime.h>

#define HW 16384        // 128*128
#define PADPIX 16900    // 130*130 padded pixel count

typedef __attribute__((ext_vector_type(8))) short short8v;
typedef __attribute__((ext_vector_type(4))) float f32x4;

__device__ inline short bf16rne(float x) {
    unsigned u = __float_as_uint(x);
    unsigned r = (u + 0x7fffu + ((u >> 16) & 1u)) >> 16;
    return (short)r;
}
__device__ inline float bf16tof(short s) {
    return __uint_as_float(((unsigned)(unsigned short)s) << 16);
}

// padded-pixel index for border element j (j in 0..515)
__device__ inline int border_pp(int j) {
    if (j < 130) return j;                          // row 0
    if (j < 260) return 129 * 130 + (j - 130);      // row 129
    if (j < 388) return (j - 259) * 130;            // col 0, rows 1..128
    return (j - 387) * 130 + 129;                   // col 129, rows 1..128
}

// ===== K1: weight prep (0..467) + borders (468..564) =========================
__global__ __launch_bounds__(256) void k1_kernel(
    const float* __restrict__ W1, const float* __restrict__ W2,
    const float* __restrict__ Wk,
    short* __restrict__ Wb1, short* __restrict__ Wb2, short* __restrict__ Wbk,
    short* __restrict__ hcatN, short* __restrict__ h1N)
{
    int bid = blockIdx.x;
    const int t = threadIdx.x;
    if (bid < 468) {
        const float* W; short* Wb; int CIN, COUT, idx;
        if (bid < 288)      { W = W1; Wb = Wb1; CIN = 128; COUT = 64; idx = bid * 256 + t; }
        else if (bid < 432) { W = W2; Wb = Wb2; CIN = 64;  COUT = 64; idx = (bid - 288) * 256 + t; }
        else                { W = Wk; Wb = Wbk; CIN = 64;  COUT = 16; idx = (bid - 432) * 256 + t; }
        int NOCT = COUT >> 4, NCH = CIN >> 5;
        int total = 9 * NCH * NOCT * 512;
        if (idx >= total) return;
        int j = idx & 7, l = (idx >> 3) & 63;
        int rest = idx >> 9;
        int oct = rest % NOCT; rest /= NOCT;
        int ch = rest % NCH;
        int tap = rest / NCH;
        int o = oct * 16 + (l & 15);
        int c = ch * 32 + (l >> 4) * 8 + j;
        Wb[idx] = bf16rne(W[((size_t)o * CIN + c) * 9 + tap]);
        return;
    }
    // ---- zero borders of hcatN (16512 int4) and h1N (8256 int4) ----
    int t2 = (bid - 468) * 256 + t;
    const int4 z = make_int4(0, 0, 0, 0);
    if (t2 < 16512) {
        int px = t2 >> 4, q = t2 & 15;
        int b = px >= 516; int j = px - b * 516;
        int pp = border_pp(j);
        ((int4*)hcatN)[((size_t)b * PADPIX + pp) * 16 + q] = z;
    } else if (t2 < 24768) {
        int idx = t2 - 16512;
        int px = idx >> 3, q = idx & 7;
        int b = px >= 516; int j = px - b * 516;
        int pp = border_pp(j);
        ((int4*)h1N)[((size_t)b * PADPIX + pp) * 8 + q] = z;
    }
}

// ===== front: upsample -> (Kf MFMA || qconv) -> gate -> hcatN, all in LDS ====
#define UPSTR 72                 // ch-stride of upB in shorts (16B-aligned)
#define UPROW (34 * UPSTR)       // shorts per upB row (34 lpx)
__global__ __launch_bounds__(256) void front_kernel(
    const float* __restrict__ x1, const short* __restrict__ Wbk,
    const float* __restrict__ bk, const float* __restrict__ Wq,
    const float* __restrict__ bq, const float* __restrict__ x2,
    const float* __restrict__ Wv, const float* __restrict__ bv,
    short* __restrict__ hcatN)
{
    __shared__ __align__(16) short upB[3 * UPROW];   // [r][lpx 0..33][ch 0..63]
    __shared__ float kfs[16 * 33];                   // [k][px 0..31], stride 33
    __shared__ float qbuf[32 * 65];                  // [px][ch], stride 65
    __shared__ int tr[32 * 33];                      // [chpair][px], stride 33
    int bid = blockIdx.x;
    const int xq = bid & 3;
    const int y = (bid >> 2) & 127;
    const int b = bid >> 9;
    const int t = threadIdx.x;
    const int X0 = xq * 32;

    // ---- phase 1: upsample rows y-1..y+1 (bf16) into upB, zeros outside ----
    {
        const int px1 = t & 31, cg1 = t >> 5;        // 32 px x 8 ch-groups
        const int gx = X0 + px1;
        float fx = (float)(gx * 63) / 127.f;
        int x0 = (int)fx; float wx = fx - (float)x0; int x1i = min(x0 + 1, 63);
        #pragma unroll
        for (int r = 0; r < 3; r++) {
            int ry = y + r - 1;
            bool rv = ((unsigned)ry < 128u);
            int ryc = rv ? ry : 0;
            float fy = (float)(ryc * 63) / 127.f;
            int y0 = (int)fy; float wy = fy - (float)y0; int y1 = min(y0 + 1, 63);
            int pk[4];
            #pragma unroll
            for (int jj = 0; jj < 4; jj++) {
                unsigned lohi[2];
                #pragma unroll
                for (int h = 0; h < 2; h++) {
                    int ch = cg1 * 8 + jj * 2 + h;
                    float v = 0.f;
                    if (rv) {
                        const float* sp = x1 + ((size_t)(b * 64 + ch) << 12);
                        float v00 = sp[(y0 << 6) + x0], v01 = sp[(y0 << 6) + x1i];
                        float v10 = sp[(y1 << 6) + x0], v11 = sp[(y1 << 6) + x1i];
                        float top = v00 * (1.f - wx) + v01 * wx;
                        float bot = v10 * (1.f - wx) + v11 * wx;
                        v = top * (1.f - wy) + bot * wy;
                    }
                    lohi[h] = (unsigned)(unsigned short)bf16rne(v);
                }
                pk[jj] = (int)(lohi[0] | (lohi[1] << 16));
            }
            *(int4*)(upB + r * UPROW + (px1 + 1) * UPSTR + cg1 * 8) =
                make_int4(pk[0], pk[1], pk[2], pk[3]);
        }
        if (t < 48) {                                // halo: r x side x cg
            int r = t >> 4, side = (t >> 3) & 1, cg = t & 7;
            int gxh = X0 + (side ? 32 : -1);
            int lpx = side ? 33 : 0;
            int ry = y + r - 1;
            bool v_ok = ((unsigned)ry < 128u) && ((unsigned)gxh < 128u);
            int ryc = ((unsigned)ry < 128u) ? ry : 0;
            float fy = (float)(ryc * 63) / 127.f;
            int y0 = (int)fy; float wy = fy - (float)y0; int y1 = min(y0 + 1, 63);
            int gxc = min(max(gxh, 0), 127);
            float fxh = (float)(gxc * 63) / 127.f;
            int hx0 = (int)fxh; float hwx = fxh - (float)hx0; int hx1 = min(hx0 + 1, 63);
            int pk[4];
            #pragma unroll
            for (int jj = 0; jj < 4; jj++) {
                unsigned lohi[2];
                #pragma unroll
                for (int h = 0; h < 2; h++) {
                    int ch = cg * 8 + jj * 2 + h;
                    float v = 0.f;
                    if (v_ok) {
                        const float* sp = x1 + ((size_t)(b * 64 + ch) << 12);
                        float v00 = sp[(y0 << 6) + hx0], v01 = sp[(y0 << 6) + hx1];
                        float v10 = sp[(y1 << 6) + hx0], v11 = sp[(y1 << 6) + hx1];
                        float top = v00 * (1.f - hwx) + v01 * hwx;
                        float bot = v10 * (1.f - hwx) + v11 * hwx;
                        v = top * (1.f - wy) + bot * wy;
                    }
                    lohi[h] = (unsigned)(unsigned short)bf16rne(v);
                }
                pk[jj] = (int)(lohi[0] | (lohi[1] << 16));
            }
            *(int4*)(upB + r * UPROW + lpx * UPSTR + cg * 8) =
                make_int4(pk[0], pk[1], pk[2], pk[3]);
        }
    }
    __syncthreads();

    // ---- phase 2: waves 0-1: Kf MFMA (16 px each); waves 2-3: qconv --------
    {
        const int w = t >> 6, l = t & 63;
        if (w < 2) {
            const int lx = l & 15, kg = l >> 4;
            const short* wbase = Wbk + (size_t)l * 8;
            f32x4 acc = (f32x4)(0.f);
            #pragma unroll
            for (int ty = 0; ty < 3; ty++) {
                #pragma unroll
                for (int tx = 0; tx < 3; tx++) {
                    const short* ab = upB + ty * UPROW + (size_t)(w * 16 + lx + tx) * UPSTR;
                    #pragma unroll
                    for (int ch = 0; ch < 2; ch++) {
                        short8v a = *(const short8v*)(ab + kg * 8 + ch * 32);
                        short8v bf = *(const short8v*)(wbase +
                            (size_t)((ty * 3 + tx) * 2 + ch) * 512);
                        acc = __builtin_amdgcn_mfma_f32_16x16x32_bf16(a, bf, acc, 0, 0, 0);
                    }
                }
            }
            float bb = bk[lx];
            #pragma unroll
            for (int r = 0; r < 4; r++)
                kfs[lx * 33 + (w * 16 + kg * 4 + r)] = fmaxf(acc[r] + bb, 0.f);
        } else {
            // depthwise qconv, ch-major sliding window (conflict-free LDS reads)
            const int ch = l;
            const int px0 = (w - 2) * 16;
            const float* wqp = Wq + ch * 9;
            float wq[9];
            #pragma unroll
            for (int i = 0; i < 9; i++) wq[i] = wqp[i];
            float bqc = bq[ch];
            float a0[3], a1[3];
            #pragma unroll
            for (int r = 0; r < 3; r++) {
                a0[r] = bf16tof(upB[r * UPROW + px0 * UPSTR + ch]);
                a1[r] = bf16tof(upB[r * UPROW + (px0 + 1) * UPSTR + ch]);
            }
            for (int p = 0; p < 16; p++) {
                float a2[3];
                #pragma unroll
                for (int r = 0; r < 3; r++)
                    a2[r] = bf16tof(upB[r * UPROW + (px0 + p + 2) * UPSTR + ch]);
                float q = bqc;
                #pragma unroll
                for (int r = 0; r < 3; r++)
                    q = fmaf(a0[r], wq[r * 3 + 0],
                        fmaf(a1[r], wq[r * 3 + 1], fmaf(a2[r], wq[r * 3 + 2], q)));
                qbuf[(px0 + p) * 65 + ch] = fmaxf(q, 0.f);
                #pragma unroll
                for (int r = 0; r < 3; r++) { a0[r] = a1[r]; a1[r] = a2[r]; }
            }
        }
    }
    __syncthreads();

    // ---- phase 3: softmax gate, 32 px x 64 ch -------------------------------
    {
        const int px = t & 31, cg = t >> 5;
        const int x = X0 + px;
        float kv[16];
        #pragma unroll
        for (int k = 0; k < 16; k++) kv[k] = kfs[k * 33 + px];
        float kvmax = kv[0];
        #pragma unroll
        for (int k = 1; k < 16; k++) kvmax = fmaxf(kvmax, kv[k]);
        float wvv[16], bvv[16];
        #pragma unroll
        for (int k = 0; k < 16; k++) { wvv[k] = Wv[k]; bvv[k] = bv[k]; }
        float xvv[8], qv[8];
        #pragma unroll
        for (int j = 0; j < 8; j++) {
            xvv[j] = x2[((size_t)(b * 64 + cg * 8 + j) << 14) + (y << 7) + x];
            qv[j] = qbuf[px * 65 + cg * 8 + j];
        }
        #pragma unroll
        for (int jj = 0; jj < 4; jj++) {
            int gpk = 0;
            #pragma unroll
            for (int h = 0; h < 2; h++) {
                const int j = jj * 2 + h;
                float q = qv[j];
                float mx = q * kvmax;                // q,kv >= 0 => exact max
                float den = 0.f, num = 0.f;
                #pragma unroll
                for (int k = 0; k < 16; k++) {
                    float e = __expf(fmaf(q, kv[k], -mx));
                    den += e;
                    float V = fmaxf(fmaf(xvv[j], wvv[k], bvv[k]), 0.f);
                    num = fmaf(e, V, num);
                }
                unsigned u = (unsigned)(unsigned short)bf16rne(num / den);
                gpk |= (int)(u << (h * 16));
            }
            tr[(cg * 4 + jj) * 33 + px] = gpk;
        }
    }
    __syncthreads();

    // ---- phase 4: coalesced writes: gate -> ch 0..63, upB row1 -> ch 64..127
    {
        const int px4 = t >> 3, cq = t & 7;
        int pp = (y + 1) * 130 + X0 + px4 + 1;
        int wd[4];
        #pragma unroll
        for (int i = 0; i < 4; i++) wd[i] = tr[(cq * 4 + i) * 33 + px4];
        int* dpL = (int*)hcatN + ((size_t)b * PADPIX + pp) * 64 + cq * 4;
        *(int4*)dpL = make_int4(wd[0], wd[1], wd[2], wd[3]);
        const short* us = upB + UPROW + (size_t)(px4 + 1) * UPSTR + cq * 8;
        int4 u = *(const int4*)us;
        int* dpU = (int*)hcatN + ((size_t)b * PADPIX + pp) * 64 + 32 + cq * 4;
        *(int4*)dpU = u;
    }
}

// ===== MFMA implicit-GEMM 3x3 conv, LDS-staged A-slab, raw-bf16 out ==========
// PADOUT: write to padded NHWC (borders stay zero); else flat NHWC [b][HW][64].
// INBN: apply BN(scale,shift)+relu inline while staging (borders forced to 0).
template<int PSTR, int LDSTR, int CIN, int COUT, int NWN, int OPW,
         bool PADOUT, bool INBN>
__global__ __launch_bounds__(256) void convmfma_kernel(
    const short* __restrict__ actN, const short* __restrict__ Wb,
    short* __restrict__ dstB,
    const float* __restrict__ statsAcc,
    const float* __restrict__ g, const float* __restrict__ beta,
    float* __restrict__ partials)
{
    constexpr int NCH = CIN / 32, NOCT = COUT / 16, NWM = 4 / NWN;
    constexpr int EXT = NWM * 16;
    constexpr int SEG = 128 / EXT;
    __shared__ __align__(16) short slab[3 * 34 * LDSTR];
    __shared__ float scsh[INBN ? 128 : 2];
    const int t = threadIdx.x;
    const int w = t >> 6, l = t & 63;
    const int wn = w % NWN, wm = w / NWN;
    int bid = blockIdx.x;
    const int xseg = bid % SEG; bid /= SEG;
    const int y = bid & 127;
    const int b = bid >> 7;
    const int lx = l & 15, kg = l >> 4;
    const int X0 = xseg * EXT;

    if (INBN) {
        if (t < 64) {
            float mean = statsAcc[t * 2] * (1.f / 32768.f);
            float var  = statsAcc[t * 2 + 1] * (1.f / 32768.f) - mean * mean;
            float sc = g[t] * rsqrtf(var + 1e-5f);
            scsh[t] = sc;
            scsh[64 + t] = beta[t] - mean * sc;
        }
        __syncthreads();
    }

    // ---- stage 3 rows x 34 px x CIN into LDS (all in-bounds of padded buf) --
    constexpr int ROWI4 = 34 * PSTR / 8;             // int4 per slab row
    constexpr int PXI4 = PSTR / 8;                   // int4 per pixel (pow2)
    #pragma unroll
    for (int r = 0; r < 3; r++) {
        const int prow = y + r;                      // padded row 0..129
        const bool rowb = (prow == 0) || (prow == 129);
        const int4* src = (const int4*)(actN +
            ((size_t)b * PADPIX + (size_t)prow * 130 + X0) * PSTR);
        for (int i = t; i < ROWI4; i += 256) {
            int p = i / PXI4, cq = i % PXI4;
            int4 v = src[i];
            if (INBN) {
                int pcol = X0 + p;                   // padded col 0..129
                if (rowb || pcol == 0 || pcol == 129) {
                    v = make_int4(0, 0, 0, 0);
                } else {
                    int ch0 = cq * 8;
                    int* vw = (int*)&v;
                    #pragma unroll
                    for (int wd = 0; wd < 4; wd++) {
                        int c0 = ch0 + wd * 2, c1 = c0 + 1;
                        float lo = bf16tof((short)(vw[wd] & 0xFFFF));
                        float hi = bf16tof((short)((unsigned)vw[wd] >> 16));
                        lo = fmaxf(fmaf(lo, scsh[c0], scsh[64 + c0]), 0.f);
                        hi = fmaxf(fmaf(hi, scsh[c1], scsh[64 + c1]), 0.f);
                        unsigned ulo = (unsigned)(unsigned short)bf16rne(lo);
                        unsigned uhi = (unsigned)(unsigned short)bf16rne(hi);
                        vw[wd] = (int)(ulo | (uhi << 16));
                    }
                }
            }
            *(int4*)(slab + (r * 34 + p) * LDSTR + cq * 8) = v;
        }
    }
    __syncthreads();

    const short* wbase = Wb + (size_t)(wn * OPW) * 512 + (size_t)l * 8;

    f32x4 acc[OPW];
    #pragma unroll
    for (int p = 0; p < OPW; p++) acc[p] = (f32x4)(0.f);

    #pragma unroll
    for (int ty = 0; ty < 3; ty++) {
        #pragma unroll
        for (int tx = 0; tx < 3; tx++) {
            const short* ab = slab + (ty * 34 + wm * 16 + lx + tx) * LDSTR + kg * 8;
            const int tap = ty * 3 + tx;
            #pragma unroll
            for (int ch = 0; ch < NCH; ch++) {
                short8v a = *(const short8v*)(ab + ch * 32);
                #pragma unroll
                for (int p = 0; p < OPW; p++) {
                    short8v bf = *(const short8v*)(wbase +
                        (size_t)((tap * NCH + ch) * NOCT + p) * 512);
                    acc[p] = __builtin_amdgcn_mfma_f32_16x16x32_bf16(a, bf, acc[p], 0, 0, 0);
                }
            }
        }
    }

    // raw bf16 epilogue (unnormalized); PADOUT keeps zero borders intact
    #pragma unroll
    for (int p = 0; p < OPW; p++) {
        const int oc = (wn * OPW + p) * 16 + lx;
        #pragma unroll
        for (int r = 0; r < 4; r++) {
            const int px_x = X0 + wm * 16 + kg * 4 + r;
            size_t pix = PADOUT
                ? ((size_t)b * PADPIX + (size_t)(y + 1) * 130 + px_x + 1)
                : ((size_t)b * HW + (size_t)y * 128 + px_x);
            dstB[pix * COUT + oc] = bf16rne(acc[p][r]);
        }
    }

    // per-wave BN partials: shfl reduce over the 4 kg groups, plain stores
    #pragma unroll
    for (int p = 0; p < OPW; p++) {
        float s = 0.f, q2 = 0.f;
        f32x4 v = acc[p];
        #pragma unroll
        for (int r = 0; r < 4; r++) { s += v[r]; q2 = fmaf(v[r], v[r], q2); }
        s += __shfl_xor(s, 16); q2 += __shfl_xor(q2, 16);
        s += __shfl_xor(s, 32); q2 += __shfl_xor(q2, 32);
        if (l < 16) {
            const int oc = (wn * OPW + p) * 16 + lx;
            float* dp = partials + (((size_t)blockIdx.x * NWM + wm) * 64 + oc) * 2;
            dp[0] = s;
            dp[1] = q2;
        }
    }
}

// ===== reduce 2048 partial pairs per channel -> raw sums (no atomics) ========
__global__ void bnred_kernel(const float* __restrict__ partials,
                             float* __restrict__ statsAcc) {
    int ch = blockIdx.x;                                 // 64 blocks
    const int t = threadIdx.x;
    float s = 0.f, q = 0.f;
    for (int i = t; i < 2048; i += 256) {
        const float* p = partials + ((size_t)i * 64 + ch) * 2;
        s += p[0];
        q += p[1];
    }
    __shared__ float sh[512];
    sh[t] = s;
    sh[256 + t] = q;
    __syncthreads();
    for (int off = 128; off > 0; off >>= 1) {
        if (t < off) {
            sh[t] += sh[t + off];
            sh[256 + t] += sh[256 + t + off];
        }
        __syncthreads();
    }
    if (t == 0) {
        statsAcc[ch * 2] = sh[0];
        statsAcc[ch * 2 + 1] = sh[256];
    }
}

// ===== BN2 finalize + relu on raw-bf16 NHWC, transpose, split -> d_out =======
// block = (b, 32-px chunk); phase A: NHWC int4 read + BN -> LDS[ch][px];
// phase B: LDS row read -> coalesced fp32 NCHW split writes.
__global__ __launch_bounds__(256) void norm2_kernel(
    const short* __restrict__ h2N, const float* __restrict__ statsAcc,
    const float* __restrict__ g, const float* __restrict__ beta,
    float* __restrict__ out)
{
    __shared__ float lds[64 * 33];
    __shared__ float scsh[128];
    int bid = blockIdx.x;
    const int chunk = bid & 511;                         // 512 chunks x 32 px
    const int b = bid >> 9;
    const int t = threadIdx.x;
    const int P0 = chunk * 32;
    if (t < 64) {
        float mean = statsAcc[t * 2] * (1.f / 32768.f);
        float var  = statsAcc[t * 2 + 1] * (1.f / 32768.f) - mean * mean;
        float sc = g[t] * rsqrtf(var + 1e-5f);
        scsh[t] = sc;
        scsh[64 + t] = beta[t] - mean * sc;
    }
    __syncthreads();
    {
        const int px = t >> 3, cq = t & 7;
        const short* sp = h2N + ((size_t)b * HW + P0 + px) * 64 + cq * 8;
        int4 v = *(const int4*)sp;
        const int* vw = (const int*)&v;
        #pragma unroll
        for (int wd = 0; wd < 4; wd++) {
            int c0 = cq * 8 + wd * 2, c1 = c0 + 1;
            float lo = bf16tof((short)(vw[wd] & 0xFFFF));
            float hi = bf16tof((short)((unsigned)vw[wd] >> 16));
            lds[c0 * 33 + px] = fmaxf(fmaf(lo, scsh[c0], scsh[64 + c0]), 0.f);
            lds[c1 * 33 + px] = fmaxf(fmaf(hi, scsh[c1], scsh[64 + c1]), 0.f);
        }
    }
    __syncthreads();
    {
        const int c = t >> 2, qx = t & 3;
        const float* r = lds + c * 33 + qx * 8;
        float4 o0, o1;
        o0.x = r[0]; o0.y = r[1]; o0.z = r[2]; o0.w = r[3];
        o1.x = r[4]; o1.y = r[5]; o1.z = r[6]; o1.w = r[7];
        int half = c >> 5, cc = c & 31;
        float* dp = out + (size_t)half * 1048576 + (((size_t)(b * 32 + cc)) << 14)
                  + P0 + qx * 8;
        *(float4*)dp = o0;
        *(float4*)(dp + 4) = o1;
    }
}

extern "C" void kernel_launch(void* const* d_in, const int* in_sizes, int n_in,
                              void* d_out, int out_size, void* d_ws, size_t ws_size,
                              hipStream_t stream) {
    const float* x1 = (const float*)d_in[0];
    // d_in[1] (x1_) is unused by the reference
    const float* x2 = (const float*)d_in[2];
    const float* Wq = (const float*)d_in[3];
    const float* bq = (const float*)d_in[4];
    const float* Wk = (const float*)d_in[5];
    const float* bk = (const float*)d_in[6];
    const float* Wv = (const float*)d_in[7];
    const float* bv = (const float*)d_in[8];
    const float* W1 = (const float*)d_in[9];
    const float* g1 = (const float*)d_in[10];
    const float* b1 = (const float*)d_in[11];
    const float* W2 = (const float*)d_in[12];
    const float* g2 = (const float*)d_in[13];
    const float* b2 = (const float*)d_in[14];
    float* out = (float*)d_out;
    float* ws = (float*)d_ws;

    // workspace layout (float offsets)
    float* stacc    = ws;                        // 256 raw sums (s1 @ +0, s2 @ +128)
    short* h2N      = (short*)(ws + 256);        // [2][HW][64] bf16  (1,048,576 f)
    short* hcatN    = (short*)(ws + 1048832);    // [2][PADPIX][128] bf16 (2,163,200 f)
    short* h1N      = (short*)(ws + 3212032);    // [2][PADPIX][64]  bf16 (1,081,600 f)
    short* Wb1      = (short*)(ws + 4293632);    // 73728 shorts = 36864 f
    short* Wb2      = (short*)(ws + 4330496);    // 36864 shorts = 18432 f
    short* Wbk      = (short*)(ws + 4348928);    // 9216 shorts  =  4608 f
    float* partials = ws + 4353536;              // 1024*2*64*2 = 262,144 f (1 MB)

    // K1: weight prep + border zeroing
    k1_kernel<<<565, 256, 0, stream>>>(W1, W2, Wk, Wb1, Wb2, Wbk, hcatN, h1N);

    // front: upsample + Kf conv + qconv + gate, fused -> hcatN (both halves)
    front_kernel<<<1024, 256, 0, stream>>>(x1, Wbk, bk, Wq, bq, x2, Wv, bv, hcatN);

    // conv1 128->64: raw bf16 -> padded NHWC h1N, fused partial stats
    convmfma_kernel<128, 136, 128, 64, 2, 2, true, false><<<1024, 256, 0, stream>>>(
        hcatN, Wb1, h1N, nullptr, nullptr, nullptr, partials);
    bnred_kernel<<<64, 256, 0, stream>>>(partials, stacc);

    // conv2 64->64: BN1+relu inline while staging; raw bf16 -> flat NHWC h2N
    convmfma_kernel<64, 72, 64, 64, 2, 2, false, true><<<1024, 256, 0, stream>>>(
        h1N, Wb2, h2N, stacc, g1, b1, partials);
    bnred_kernel<<<64, 256, 0, stream>>>(partials, stacc + 128);

    // BN2 finalize + relu + transpose + split -> d_out
    norm2_kernel<<<1024, 256, 0, stream>>>(h2N, stacc + 128, g2, b2, out);
}